// Round 13
// baseline (420.690 us; speedup 1.0000x reference)
//
#include <hip/hip_runtime.h>
#include <hip/hip_bf16.h>
#include <stdint.h>

// Problem constants: B=4, S=1024, E=1024, H=16, D=64
// Dtypes (r0-r9 proven): ALL inputs fp32 (mask int32), outputs fp32.
#define BATCH 4
#define SEQ   1024
#define EMB   1024
#define NH    16
#define HD    64

typedef short s8v __attribute__((ext_vector_type(8)));   // 8 bf16 (A/B frag)
typedef float f4v __attribute__((ext_vector_type(4)));   // 4 fp32 (C/D frag)

__device__ __forceinline__ uint16_t f2bf(float f) {
    __hip_bfloat16 h = __float2bfloat16(f);
    return *reinterpret_cast<uint16_t*>(&h);
}
__device__ __forceinline__ short bfraw(float f) {
    __hip_bfloat16 h = __float2bfloat16(f);
    return *reinterpret_cast<short*>(&h);
}
// Load 8 consecutive fp32, pack to 8-wide bf16 fragment.
__device__ __forceinline__ s8v cvt8(const float* p) {
    float4 a = *(const float4*)p;
    float4 b = *(const float4*)(p + 4);
    s8v r;
    r[0] = bfraw(a.x); r[1] = bfraw(a.y); r[2] = bfraw(a.z); r[3] = bfraw(a.w);
    r[4] = bfraw(b.x); r[5] = bfraw(b.y); r[6] = bfraw(b.z); r[7] = bfraw(b.w);
    return r;
}
// Async global->LDS, 16B/lane. LDS dest = wave-uniform base + lane*16 (HW).
__device__ __forceinline__ void gld16(const uint16_t* g, uint16_t* l) {
    __builtin_amdgcn_global_load_lds(
        (const __attribute__((address_space(1))) void*)g,
        (__attribute__((address_space(3))) void*)l, 16, 0, 0);
}

// Bitpack mask: int32 [B,S,S] -> 1 bit/elem (512 KB).
__global__ __launch_bounds__(256) void pack_mask(
        const int* __restrict__ mask, unsigned long long* __restrict__ Mb64)
{
    const size_t gid = (size_t)blockIdx.x * 256 + threadIdx.x;
    const unsigned long long bal = __ballot(mask[gid] != 0);
    if ((threadIdx.x & 63) == 0) Mb64[gid >> 6] = bal;
}

// Prepass: convert 4 weight matrices + 3 activation inputs fp32->bf16.
__global__ __launch_bounds__(256) void cvt_all(
        const float* __restrict__ W0, const float* __restrict__ W1,
        const float* __restrict__ W2, const float* __restrict__ W3,
        const float* __restrict__ X0, const float* __restrict__ X1,
        const float* __restrict__ X2,
        uint16_t* __restrict__ Wdst, uint16_t* __restrict__ Xq,
        uint16_t* __restrict__ Xk, uint16_t* __restrict__ Xv)
{
    const int y = blockIdx.y;
    const size_t off = ((size_t)blockIdx.x * 256 + threadIdx.x) * 8;
    if (y < 4) {
        if (blockIdx.x >= 512) return;               // W: 1Mi elems
        const float* s = (y == 0) ? W0 : (y == 1) ? W1 : (y == 2) ? W2 : W3;
        *(s8v*)(Wdst + (size_t)y * EMB * EMB + off) = cvt8(s + off);
    } else {
        const float* s = (y == 4) ? X0 : (y == 5) ? X1 : X2;
        uint16_t*    d = (y == 4) ? Xq : (y == 5) ? Xk : Xv;
        *(s8v*)(d + off) = cvt8(s + off);
    }
}

// Triple-GEMM, m97 structure (r13 = audited r11): 128x128 tile, BK=32,
// 256 thr = 4 waves (2x2, wave tile 64x64 -> 16 MFMA : 8 ds_read per step),
// double-buffered LDS filled by ASYNC global_load_lds (no VGPR round-trip),
// ONE barrier per K-step. Loads for tile k+1 issue right after the barrier
// and stay in flight across the whole compute phase; their drain lands at
// the NEXT iteration's barrier (r6-r12 reg-staging sat at ~165 TF; the
// ladder's m93->m97 step for this exact change was 517->874 TF).
// Race-safe with one barrier: all reads of buf[c] precede barrier_k; all
// DMA issues into buf[c] follow it.
// Bank conflicts: global_load_lds needs a LINEAR LDS dest, so the per-lane
// GLOBAL source is pre-swizzled instead (m173/m201): row r's 16B-slot p
// holds logical slot p ^ ((r>>1)&3); reads apply the same XOR
// (sl = aq ^ ((ar>>1)&3); (r>>1)&3 reduces correctly since 8i = 0 mod 4).
// blockIdx.z picks the projection (QKV fused in one dispatch).
// scatter==1: bf16 [B,H,S,D]. scatter==2: bf16 [B,H,D,S]. scatter==0: fp32 [M][N].
__global__ __launch_bounds__(256) void gemm3(
        const uint16_t* __restrict__ X0, const uint16_t* __restrict__ W0,
        const float* __restrict__ b0, void* __restrict__ o0, int sc0, float ss0,
        const uint16_t* __restrict__ X1, const uint16_t* __restrict__ W1,
        const float* __restrict__ b1, void* __restrict__ o1, int sc1, float ss1,
        const uint16_t* __restrict__ X2, const uint16_t* __restrict__ W2,
        const float* __restrict__ b2, void* __restrict__ o2, int sc2, float ss2)
{
    __shared__ __attribute__((aligned(16))) uint16_t As[2][128 * 32];
    __shared__ __attribute__((aligned(16))) uint16_t Bs[2][128 * 32];

    const int z = blockIdx.z;
    const uint16_t* Xb   = (z == 0) ? X0 : (z == 1) ? X1 : X2;
    const uint16_t* Wb   = (z == 0) ? W0 : (z == 1) ? W1 : W2;
    const float*    bias = (z == 0) ? b0 : (z == 1) ? b1 : b2;
    void*           outv = (z == 0) ? o0 : (z == 1) ? o1 : o2;
    const int     scatter = (z == 0) ? sc0 : (z == 1) ? sc1 : sc2;
    const float   scale   = (z == 0) ? ss0 : (z == 1) ? ss1 : ss2;

    const int t    = threadIdx.x;
    const int lane = t & 63;
    const int w    = t >> 6;              // 0..3
    const int wm = w & 1;                 // m half (64 rows)
    const int wn = w >> 1;                // n half (64 cols)
    const int m0 = blockIdx.y * 128;
    const int n0 = blockIdx.x * 128;
    const int ar = lane & 15;             // fragment row
    const int aq = lane >> 4;             // quad -> k offset aq*8

    // staging map: wave w covers tile rows [w*32, w*32+32) as 2 chunks of 16.
    // lane l -> row w*32 + c*16 + (l>>2), 16B-slot l&3. Swizzled source col:
    // slot ^ ((row>>1)&3) = (l&3) ^ ((l>>3)&3).
    const int srow = w * 32 + (lane >> 2);
    const int scol = ((lane & 3) ^ ((lane >> 3) & 3)) * 8;
    const uint16_t* gA0 = Xb + (size_t)(m0 + srow) * EMB + scol;
    const uint16_t* gA1 = gA0 + (size_t)16 * EMB;
    const uint16_t* gB0 = Wb + (size_t)(n0 + srow) * EMB + scol;
    const uint16_t* gB1 = gB0 + (size_t)16 * EMB;
    const int lb0 = w * 1024;             // elems: w*32 rows * 32 cols
    const int lb1 = lb0 + 512;            // +16 rows

    f4v acc[4][4];
    #pragma unroll
    for (int i = 0; i < 4; ++i)
        #pragma unroll
        for (int j = 0; j < 4; ++j) acc[i][j] = (f4v){0.f, 0.f, 0.f, 0.f};

    // prologue: tile 0 -> buf 0
    gld16(gA0, &As[0][lb0]); gld16(gA1, &As[0][lb1]);
    gld16(gB0, &Bs[0][lb0]); gld16(gB1, &Bs[0][lb1]);

    const int sl = (aq ^ ((ar >> 1) & 3)) * 8;   // swizzled read slot (elems)

    for (int ki = 0; ki < 32; ++ki) {
        __syncthreads();   // vmcnt drained -> buf[ki&1] staged; prev readers done
        if (ki + 1 < 32) {
            const int kn = (ki + 1) * 32;
            const int nb = (ki + 1) & 1;
            gld16(gA0 + kn, &As[nb][lb0]); gld16(gA1 + kn, &As[nb][lb1]);
            gld16(gB0 + kn, &Bs[nb][lb0]); gld16(gB1 + kn, &Bs[nb][lb1]);
        }
        const uint16_t* Ab = &As[ki & 1][0];
        const uint16_t* Bb = &Bs[ki & 1][0];
        s8v af[4], bf[4];
        #pragma unroll
        for (int i = 0; i < 4; ++i)
            af[i] = *(const s8v*)(Ab + (wm * 64 + i * 16 + ar) * 32 + sl);
        #pragma unroll
        for (int j = 0; j < 4; ++j)
            bf[j] = *(const s8v*)(Bb + (wn * 64 + j * 16 + ar) * 32 + sl);
        #pragma unroll
        for (int i = 0; i < 4; ++i)
            #pragma unroll
            for (int j = 0; j < 4; ++j)
                acc[i][j] = __builtin_amdgcn_mfma_f32_16x16x32_bf16(af[i], bf[j], acc[i][j], 0, 0, 0);
    }

    // C/D layout: col = lane&15 (n), row = (lane>>4)*4 + r (m)  [m89]
    #pragma unroll
    for (int i = 0; i < 4; ++i) {
        const int crow = m0 + wm * 64 + i * 16 + aq * 4;
        #pragma unroll
        for (int j = 0; j < 4; ++j) {
            const int n = n0 + wn * 64 + j * 16 + ar;
            const float bv = bias[n];
            #pragma unroll
            for (int r = 0; r < 4; ++r) {
                const int m = crow + r;
                const float v = (acc[i][j][r] + bv) * scale;
                if (scatter == 1) {
                    size_t idx = (size_t)(((m >> 10) * NH + (n >> 6)) * SEQ + (m & 1023)) * HD + (n & 63);
                    ((uint16_t*)outv)[idx] = f2bf(v);
                } else if (scatter == 2) {
                    size_t idx = (size_t)(((m >> 10) * NH + (n >> 6)) * HD + (n & 63)) * SEQ + (m & 1023);
                    ((uint16_t*)outv)[idx] = f2bf(v);
                } else {
                    ((float*)outv)[(size_t)m * EMB + n] = v;
                }
            }
        }
    }
}

// Flash ctx: r9 version VERBATIM (123 us, proven local optimum; benched clean).
__global__ __launch_bounds__(256, 4) void flash_ctx(
        const uint16_t* __restrict__ Qb, const uint16_t* __restrict__ Kb,
        const uint16_t* __restrict__ Vt, const uint32_t* __restrict__ Mb,
        uint16_t* __restrict__ ctx, float* __restrict__ linv_out)
{
    __shared__ uint32_t Ml[4][16][33];                                 // mask bits
    __shared__ __attribute__((aligned(16))) uint16_t Pt[4][2][16][56]; // P^T, per stream

    const int t = threadIdx.x;
    const int w = t >> 6, lane = t & 63;
    const int ar = lane & 15, aq = lane >> 4;

    const int id   = blockIdx.x;            // 0..1023
    const int xcd  = id & 7;
    const int rest = id >> 3;               // 0..127
    const int bh   = xcd * 8 + (rest & 7);  // same (b,h) -> same XCD
    const int qt   = (rest >> 3) * 4 + w;   // 0..63, per-wave
    const int b = bh >> 4, h = bh & 15;
    const size_t hb = ((size_t)(b * NH + h)) * SEQ * HD;

    // stage this wave's 16 q-rows of mask bits (512 u32, coalesced)
    {
        const uint32_t* src = Mb + (((size_t)b * SEQ + qt * 16) << 5);
        uint4 m0 = *(const uint4*)(src + lane * 8);
        uint4 m1 = *(const uint4*)(src + lane * 8 + 4);
        const int pr = (lane * 8) >> 5, pc = (lane * 8) & 31;
        Ml[w][pr][pc + 0] = m0.x; Ml[w][pr][pc + 1] = m0.y;
        Ml[w][pr][pc + 2] = m0.z; Ml[w][pr][pc + 3] = m0.w;
        Ml[w][pr][pc + 4] = m1.x; Ml[w][pr][pc + 5] = m1.y;
        Ml[w][pr][pc + 6] = m1.z; Ml[w][pr][pc + 7] = m1.w;
    }

    const uint16_t* qp = Qb + hb + (size_t)(qt * 16 + ar) * HD + aq * 8;
    const s8v a0 = *(const s8v*)qp;
    const s8v a1 = *(const s8v*)(qp + 32);

    const uint16_t* kbase = Kb + hb + (size_t)ar * HD + aq * 8;
    const uint16_t* vbase = Vt + hb + (size_t)ar * SEQ + aq * 8;

    f4v OA0 = {0.f,0.f,0.f,0.f}, OA1 = OA0, OA2 = OA0, OA3 = OA0;
    f4v OB0 = OA0, OB1 = OA0, OB2 = OA0, OB3 = OA0;
    float lsA[4] = {0.f, 0.f, 0.f, 0.f};
    float lsB[4] = {0.f, 0.f, 0.f, 0.f};

    for (int ci = 0; ci < 16; ++ci) {
        const int cA = ci * 2, cB = ci * 2 + 1;
        const int kcA = cA * 32, kcB = cB * 32;

        const uint16_t* kA = kbase + (size_t)kcA * HD;
        const uint16_t* kB = kbase + (size_t)kcB * HD;
        s8v Abl0 = *(const s8v*)kA,            Abh0 = *(const s8v*)(kA + 32);
        s8v Abl1 = *(const s8v*)(kA + 16*HD),  Abh1 = *(const s8v*)(kA + 16*HD + 32);
        s8v Bbl0 = *(const s8v*)kB,            Bbh0 = *(const s8v*)(kB + 32);
        s8v Bbl1 = *(const s8v*)(kB + 16*HD),  Bbh1 = *(const s8v*)(kB + 16*HD + 32);

        f4v z = {0.f,0.f,0.f,0.f};
        f4v sA0 = __builtin_amdgcn_mfma_f32_16x16x32_bf16(a0, Abl0, z, 0, 0, 0);
        sA0 = __builtin_amdgcn_mfma_f32_16x16x32_bf16(a1, Abh0, sA0, 0, 0, 0);
        f4v sA1 = __builtin_amdgcn_mfma_f32_16x16x32_bf16(a0, Abl1, z, 0, 0, 0);
        sA1 = __builtin_amdgcn_mfma_f32_16x16x32_bf16(a1, Abh1, sA1, 0, 0, 0);
        f4v sB0 = __builtin_amdgcn_mfma_f32_16x16x32_bf16(a0, Bbl0, z, 0, 0, 0);
        sB0 = __builtin_amdgcn_mfma_f32_16x16x32_bf16(a1, Bbh0, sB0, 0, 0, 0);
        f4v sB1 = __builtin_amdgcn_mfma_f32_16x16x32_bf16(a0, Bbl1, z, 0, 0, 0);
        sB1 = __builtin_amdgcn_mfma_f32_16x16x32_bf16(a1, Bbh1, sB1, 0, 0, 0);

        const uint16_t* vA = vbase + kcA;
        const uint16_t* vB = vbase + kcB;
        s8v Av0 = *(const s8v*)(vA);
        s8v Av1 = *(const s8v*)(vA + 16 * SEQ);
        s8v Av2 = *(const s8v*)(vA + 32 * SEQ);
        s8v Av3 = *(const s8v*)(vA + 48 * SEQ);
        s8v Bv0 = *(const s8v*)(vB);
        s8v Bv1 = *(const s8v*)(vB + 16 * SEQ);
        s8v Bv2 = *(const s8v*)(vB + 32 * SEQ);
        s8v Bv3 = *(const s8v*)(vB + 48 * SEQ);

        #pragma unroll
        for (int r = 0; r < 4; ++r) {
            const uint32_t mwA = Ml[w][aq * 4 + r][cA];
            const float e0 = ((mwA >> ar) & 1u)        ? __expf(sA0[r]) : 0.f;
            const float e1 = ((mwA >> (16 + ar)) & 1u) ? __expf(sA1[r]) : 0.f;
            lsA[r] += e0 + e1;
            Pt[w][0][aq * 4 + r][ar]      = f2bf(e0);
            Pt[w][0][aq * 4 + r][16 + ar] = f2bf(e1);
        }
        #pragma unroll
        for (int r = 0; r < 4; ++r) {
            const uint32_t mwB = Ml[w][aq * 4 + r][cB];
            const float e0 = ((mwB >> ar) & 1u)        ? __expf(sB0[r]) : 0.f;
            const float e1 = ((mwB >> (16 + ar)) & 1u) ? __expf(sB1[r]) : 0.f;
            lsB[r] += e0 + e1;
            Pt[w][1][aq * 4 + r][ar]      = f2bf(e0);
            Pt[w][1][aq * 4 + r][16 + ar] = f2bf(e1);
        }

        const s8v paA = *(const s8v*)&Pt[w][0][ar][aq * 8];
        OA0 = __builtin_amdgcn_mfma_f32_16x16x32_bf16(paA, Av0, OA0, 0, 0, 0);
        OA1 = __builtin_amdgcn_mfma_f32_16x16x32_bf16(paA, Av1, OA1, 0, 0, 0);
        OA2 = __builtin_amdgcn_mfma_f32_16x16x32_bf16(paA, Av2, OA2, 0, 0, 0);
        OA3 = __builtin_amdgcn_mfma_f32_16x16x32_bf16(paA, Av3, OA3, 0, 0, 0);
        const s8v paB = *(const s8v*)&Pt[w][1][ar][aq * 8];
        OB0 = __builtin_amdgcn_mfma_f32_16x16x32_bf16(paB, Bv0, OB0, 0, 0, 0);
        OB1 = __builtin_amdgcn_mfma_f32_16x16x32_bf16(paB, Bv1, OB1, 0, 0, 0);
        OB2 = __builtin_amdgcn_mfma_f32_16x16x32_bf16(paB, Bv2, OB2, 0, 0, 0);
        OB3 = __builtin_amdgcn_mfma_f32_16x16x32_bf16(paB, Bv3, OB3, 0, 0, 0);
    }

    float lsum[4];
    #pragma unroll
    for (int r = 0; r < 4; ++r) {
        OA0[r] += OB0[r]; OA1[r] += OB1[r];
        OA2[r] += OB2[r]; OA3[r] += OB3[r];
        lsum[r] = lsA[r] + lsB[r];
    }

    #pragma unroll
    for (int off = 1; off < 16; off <<= 1) {
        #pragma unroll
        for (int r = 0; r < 4; ++r) lsum[r] += __shfl_xor(lsum[r], off);
    }
    float inv[4];
    #pragma unroll
    for (int r = 0; r < 4; ++r) inv[r] = 1.0f / lsum[r];

    #pragma unroll
    for (int r = 0; r < 4; ++r) {
        const int q = qt * 16 + aq * 4 + r;
        uint16_t* cp = ctx + ((size_t)(b * SEQ + q) * NH + h) * HD + ar;
        cp[ 0] = f2bf(OA0[r] * inv[r]);
        cp[16] = f2bf(OA1[r] * inv[r]);
        cp[32] = f2bf(OA2[r] * inv[r]);
        cp[48] = f2bf(OA3[r] * inv[r]);
    }
    if (ar == 0) {
        #pragma unroll
        for (int r = 0; r < 4; ++r)
            linv_out[(size_t)(b * NH + h) * SEQ + qt * 16 + aq * 4 + r] = inv[r];
    }
}

// attn_avg: recompute QK^T, apply exp * (1/l) * (1/16), sum over ALL 16 heads
// in regs, write FINAL attn_out. Block (qt, b*4+kq), 8 waves, wave w owns k in
// [kq*256 + w*32, +32). Grid 1024. No barriers, no LDS. (r8 version, proven.)
__global__ __launch_bounds__(512, 4) void attn_avg(
        const uint16_t* __restrict__ Qb, const uint16_t* __restrict__ Kb,
        const uint32_t* __restrict__ Mb, const float* __restrict__ linv,
        float* __restrict__ attn_out)
{
    const int qt = blockIdx.x;
    const int b  = blockIdx.y >> 2;
    const int kq = blockIdx.y & 3;
    const int t = threadIdx.x;
    const int w = t >> 6, lane = t & 63;
    const int ar = lane & 15, aq = lane >> 4;
    const int k0 = kq * 256 + w * 32;

    uint32_t mw[4];
    #pragma unroll
    for (int r = 0; r < 4; ++r)
        mw[r] = Mb[(((size_t)b * SEQ + qt * 16 + aq * 4 + r) << 5) + (k0 >> 5)];

    float acc[8];
    #pragma unroll
    for (int j = 0; j < 8; ++j) acc[j] = 0.f;

    for (int h = 0; h < NH; ++h) {
        const size_t hb = ((size_t)(b * NH + h)) * SEQ * HD;
        const uint16_t* qp = Qb + hb + (size_t)(qt * 16 + ar) * HD + aq * 8;
        const s8v a0 = *(const s8v*)qp;
        const s8v a1 = *(const s8v*)(qp + 32);
        float fs[4];
        #pragma unroll
        for (int r = 0; r < 4; ++r)
            fs[r] = linv[(size_t)(b * NH + h) * SEQ + qt * 16 + aq * 4 + r] * 0.0625f;

        #pragma unroll
        for (int nt = 0; nt < 2; ++nt) {
            const uint16_t* kp = Kb + hb + (size_t)(k0 + nt * 16 + ar) * HD + aq * 8;
            s8v bl = *(const s8v*)kp, bh2 = *(const s8v*)(kp + 32);
            f4v z = {0.f,0.f,0.f,0.f};
            f4v s = __builtin_amdgcn_mfma_f32_16x16x32_bf16(a0, bl, z, 0, 0, 0);
            s = __builtin_amdgcn_mfma_f32_16x16x32_bf16(a1, bh2, s, 0, 0, 0);
            #pragma unroll
            for (int r = 0; r < 4; ++r) {
                const int bit = nt * 16 + ar;
                if ((mw[r] >> bit) & 1u) acc[r * 2 + nt] += __expf(s[r]) * fs[r];
            }
        }
    }

    #pragma unroll
    for (int r = 0; r < 4; ++r) {
        float* ap = attn_out + ((size_t)b * SEQ + qt * 16 + aq * 4 + r) * SEQ + k0 + ar;
        #pragma unroll
        for (int nt = 0; nt < 2; ++nt) ap[nt * 16] = acc[r * 2 + nt];
    }
}

extern "C" void kernel_launch(void* const* d_in, const int* in_sizes, int n_in,
                              void* d_out, int out_size, void* d_ws, size_t ws_size,
                              hipStream_t stream) {
    const float* q_in = (const float*)d_in[0];
    const float* k_in = (const float*)d_in[1];
    const float* v_in = (const float*)d_in[2];
    const int*   mask = (const int*)d_in[3];
    const float* Wq = (const float*)d_in[4];
    const float* bq = (const float*)d_in[5];
    const float* Wk = (const float*)d_in[6];
    const float* bk = (const float*)d_in[7];
    const float* Wv = (const float*)d_in[8];
    const float* bv = (const float*)d_in[9];
    const float* Wo = (const float*)d_in[10];
    const float* bo = (const float*)d_in[11];

    float* out      = (float*)d_out;                         // [B,S,E] fp32
    float* attn_out = out + (size_t)BATCH * SEQ * EMB;       // [B,S,S] fp32

    const size_t qkv_elems = (size_t)BATCH * NH * SEQ * HD;  // 4 Mi
    uint16_t* Qb  = (uint16_t*)d_ws;                         // [B,H,S,D] bf16 (pre-scaled 1/8)
    uint16_t* Kb  = Qb + qkv_elems;                          // [B,H,S,D] bf16
    uint16_t* Vt  = Kb + qkv_elems;                          // [B,H,D,S] bf16 (transposed!)
    uint16_t* ctx = Vt + qkv_elems;                          // [B,S,E] bf16
    uint16_t* Wcb = ctx + (size_t)BATCH * SEQ * EMB;         // 4x [E,E] bf16 (8 MB)
    uint16_t* Wqb = Wcb;
    uint16_t* Wkb = Wcb + (size_t)EMB * EMB;
    uint16_t* Wvb = Wcb + 2 * (size_t)EMB * EMB;
    uint16_t* Wob = Wcb + 3 * (size_t)EMB * EMB;
    uint16_t* Xq  = Wcb + 4 * (size_t)EMB * EMB;             // [B,S,E] bf16 (8 MB)
    uint16_t* Xk  = Xq + qkv_elems;                          // [B,S,E] bf16 (8 MB)
    uint16_t* Xv  = ctx;   // alias: Xv consumed by V-proj BEFORE attn writes ctx
    uint32_t* Mb32 = (uint32_t*)(Xk + qkv_elems);            // bitpacked mask (512 KB)
    float*    linv = (float*)(Mb32 + (size_t)BATCH * SEQ * 32); // [B,H,S] 1/l (256 KB)

    // prepasses: mask bitpack + all fp32->bf16 conversions
    pack_mask<<<dim3((BATCH * SEQ * SEQ) / 256), 256, 0, stream>>>(
        mask, (unsigned long long*)Mb32);
    cvt_all<<<dim3(2048, 7), 256, 0, stream>>>(Wq, Wk, Wv, Wo, q_in, k_in, v_in,
                                               Wcb, Xq, Xk, Xv);

    // fused QKV projections: async-LDS m97-structure GEMM, one dispatch
    dim3 g3(EMB / 128, (BATCH * SEQ) / 128, 3);              // 8 x 32 x 3
    gemm3<<<g3, 256, 0, stream>>>(
        Xq, Wqb, bq, Qb, 1, 0.125f,
        Xk, Wkb, bk, Kb, 1, 1.0f,
        Xv, Wvb, bv, Vt, 2, 1.0f);

    // dual-stream flash ctx (r9 verbatim), then head-summed attn_avg
    flash_ctx<<<dim3(1024), 256, 0, stream>>>(Qb, Kb, Vt, Mb32, ctx, linv);
    attn_avg<<<dim3(SEQ / 16, BATCH * 4), 512, 0, stream>>>(Qb, Kb, Mb32, linv, attn_out);

    // O projection (same kernel, z-grid of 1)
    dim3 g1(EMB / 128, (BATCH * SEQ) / 128, 1);
    gemm3<<<g1, 256, 0, stream>>>(
        ctx, Wob, bo, out, 0, 1.0f,
        ctx, Wob, bo, out, 0, 1.0f,
        ctx, Wob, bo, out, 0, 1.0f);
}